// Round 9
// baseline (173.779 us; speedup 1.0000x reference)
//
#include <hip/hip_runtime.h>
#include <hip/hip_bf16.h>
#include <hip/hip_fp16.h>

typedef unsigned short u16;
typedef unsigned int u32;
typedef __attribute__((ext_vector_type(4))) short short4v;  // mfma 16x16x16 A/B frag (2 VGPRs)
typedef __attribute__((ext_vector_type(4))) float f32x4;    // mfma C/D frag
typedef __attribute__((ext_vector_type(2))) _Float16 half2v; // packed fp16 pair

#define NN 30
#define FF 4
#define EE 870
#define BSZ 32
#define CC 64
#define TT 128
#define NF 120
#define TSTRIDE 15240
#define OUTHALF 487680
#define AST 68            // S row stride (u16); 17-dw stride -> 2-way max on frag reads (free)
#define WST 68            // LDS weight row stride (u16)
#define NSETS 4           // channel-sets per block (share one weight copy)
#define NCPB 2            // channels per set, processed CONCURRENTLY (R9)
#define BPB  8            // blocks per bs -> grid 256 = 1 block/CU

// R9: CONCURRENT channels. R8 ledger: G(stage)~18us + 2*L(channel)~19us = 56us
// dispatch, 12 barriers/block forcing phase lockstep (MfmaUtil 9% while
// VALU idles in MFMA phase and vice versa). Both channels of a set are
// independent -> run them inside the SAME barrier regions:
//   merged edge phase (rows of ch0+ch1 interleaved; two independent dot2
//   chains/iter; mask SALU shared - same graph for both), then merged MLP
//   phase (two MFMA chains back-to-back). Barriers 12 -> 6.
// LDS 64.5 -> 83.6 KB: free, we are at 1 block/CU regardless.
// Numerics per channel byte-identical to R6/R7/R8 PASSING kernels.

__device__ __forceinline__ float bf2f(u16 u) {
    union { u32 i; float f; } v; v.i = ((u32)u) << 16; return v.f;
}
// fast RNE f32->bf16 (finite values): ~4 VALU instead of libcall sequence
__device__ __forceinline__ u16 f2bf_fast(float f) {
    union { float f; u32 u; } v; v.f = f;
    return (u16)((v.u + 0x7FFFu + ((v.u >> 16) & 1u)) >> 16);
}
__device__ __forceinline__ float ldv(const void* p, int idx, int isbf) {
    if (isbf) return bf2f(((const u16*)p)[idx]);
    return ((const float*)p)[idx];
}
// fast softplus+clip: v_exp/v_log based. Matches exact path at both clip
// boundaries (large +z: log(1+0)=0; very -z: underflows to 0 then clips to 1e-8).
__device__ __forceinline__ float softplus_clip(float z) {
    float t = __expf(-fabsf(z));
    float sp = fmaxf(z, 0.f) + __logf(1.f + t);
    return fminf(fmaxf(sp, 1e-8f), 100.f);
}
__device__ __forceinline__ f32x4 MFMA16(short4v a, short4v b, f32x4 c) {
    return __builtin_amdgcn_mfma_f32_16x16x16bf16_1k(a, b, c, 0, 0, 0);
}

__device__ __forceinline__ int probe_isbf(const u16* g, int lane) {
    int hit = (g[2 * lane] == 0x3F80u) | (g[128 + 2 * lane] == 0x3F80u);
    unsigned long long b = __ballot(hit);
    return (b != 0ull) ? 1 : 0;
}

// LDS = 43520(W) + 8*4352(S) + 8*480(xN) + 128 gmask + 1280 bias = 83584 B.
// launch_bounds(1024, 4): VGPR cap 128; ~75-90 VGPR expected (no spill).
// NOTE: (1024, 8) regressed badly: 64-VGPR cap forced scratch spill. Keep 4.
__global__ __launch_bounds__(1024, 4)
void sim_fused(const void* __restrict__ data,
               const void* __restrict__ graph,
               const void* __restrict__ mW1, const void* __restrict__ mB1,
               const void* __restrict__ mW2, const void* __restrict__ mB2,
               const void* __restrict__ aW1, const void* __restrict__ aB1,
               const void* __restrict__ aW2, const void* __restrict__ aB2,
               const void* __restrict__ aW3, const void* __restrict__ aB3,
               const void* __restrict__ vW1, const void* __restrict__ vB1,
               const void* __restrict__ vW2, const void* __restrict__ vB2,
               const void* __restrict__ vW3, const void* __restrict__ vB3,
               void* __restrict__ out)
{
    __shared__ __align__(16) float xN[NSETS][NCPB][NF];
    __shared__ __align__(16) u32 gmaskS[32];
    __shared__ __align__(16) u16 S[NSETS * NCPB][32 * AST];
    __shared__ __align__(16) u16 lwM2[64 * WST];
    __shared__ __align__(16) u16 lwH1m[64 * WST];
    __shared__ __align__(16) u16 lwH2m[64 * WST];
    __shared__ __align__(16) u16 lwH1v[64 * WST];
    __shared__ __align__(16) u16 lwH2v[64 * WST];
    __shared__ __align__(16) float biasL[5 * 64];  // mB2|aB1|aB2|vB1|vB2

    const int tid  = threadIdx.x;
    const int lane = tid & 63;
    const int wv   = tid >> 6;        // 0..15
    const int set  = wv >> 2;         // 0..3 : channel-set
    const int swv  = wv & 3;          // 0..3 within set
    const int ln15 = lane & 15;
    const int quad = lane >> 4;
    const int bs   = blockIdx.x / BPB;
    const int bg   = blockIdx.x % BPB;
    const int cg   = bg * NSETS + set; // channel group 0..31 (NCPB channels each)
    const int isbf = probe_isbf((const u16*)graph, lane);

    const bool isMean = (swv < 2);
    const int nb = swv & 1;           // this wave's 16-node block

    // ---- phase 0: zero gmask + S pad rows ----
    if (tid < 32) gmaskS[tid] = 0u;
    {   // zero pad rows 30,31 of all 8 S buffers (stay zero forever): 8*2*64=1024
        int s2 = tid >> 7, row = 30 + ((tid >> 6) & 1);
        S[s2][row * AST + (tid & 63)] = 0;
    }
    __syncthreads();   // gmask zeroing visible before atomics

    // ---- phase 1: one-time staging (masks, weights transposed, biases, xN) ----
    if (tid < EE) {    // coalesced: graph row for this bs is contiguous
        int i = tid / 29;
        int e = tid - i * 29;
        if (ldv(graph, bs * EE + tid, isbf) > 0.5f)
            atomicOr(&gmaskS[i], 1u << e);
    }
    // transpose five 64x64 weights into LDS o-major rows (stride WST).
    if (isbf) {
        // bf16 source: u32 loads (2 o's per load), raw u16 writes
        // (f2bf(bf2f(x)) is identity -> numerics unchanged vs scalar path)
        for (int idx2 = tid; idx2 < 2048; idx2 += 1024) {  // 2 iters x 5 arrays
            int k = idx2 >> 5, o = (idx2 & 31) * 2;
            int d0 = o * WST + k, d1 = d0 + WST;
            u32 w;
            w = ((const u32*)mW2)[idx2]; lwM2[d0]  = (u16)w; lwM2[d1]  = (u16)(w >> 16);
            w = ((const u32*)aW1)[idx2]; lwH1m[d0] = (u16)w; lwH1m[d1] = (u16)(w >> 16);
            w = ((const u32*)aW2)[idx2]; lwH2m[d0] = (u16)w; lwH2m[d1] = (u16)(w >> 16);
            w = ((const u32*)vW1)[idx2]; lwH1v[d0] = (u16)w; lwH1v[d1] = (u16)(w >> 16);
            w = ((const u32*)vW2)[idx2]; lwH2v[d0] = (u16)w; lwH2v[d1] = (u16)(w >> 16);
        }
    } else {
        for (int idx = tid; idx < 4096; idx += 1024) {  // 4 iters x 5 arrays
            int k = idx >> 6, o = idx & 63;
            int d = o * WST + k;
            lwM2[d]  = f2bf_fast(((const float*)mW2)[idx]);
            lwH1m[d] = f2bf_fast(((const float*)aW1)[idx]);
            lwH2m[d] = f2bf_fast(((const float*)aW2)[idx]);
            lwH1v[d] = f2bf_fast(((const float*)vW1)[idx]);
            lwH2v[d] = f2bf_fast(((const float*)vW2)[idx]);
        }
    }
    if (tid < 64) {
        biasL[tid]       = ldv(mB2, tid, isbf);
        biasL[64 + tid]  = ldv(aB1, tid, isbf);
        biasL[128 + tid] = ldv(aB2, tid, isbf);
        biasL[192 + tid] = ldv(vB1, tid, isbf);
        biasL[256 + tid] = ldv(vB2, tid, isbf);
    }
    // stage BOTH channels' features for this set
    {
        const int setTid = tid & 255;
#pragma unroll
        for (int ci = 0; ci < NCPB; ci++) {
            const int c = cg * NCPB + ci;
            if (isbf) {
                if (setTid < 60) {
                    u32 w = ((const u32*)data)[((bs * TT + 2 * c) * NF) / 2 + setTid];
                    xN[set][ci][setTid * 2]     = bf2f((u16)(w & 0xFFFF));
                    xN[set][ci][setTid * 2 + 1] = bf2f((u16)(w >> 16));
                }
            } else {
                if (setTid < NF)
                    xN[set][ci][setTid] = ((const float*)data)[(bs * TT + 2 * c) * NF + setTid];
            }
        }
    }

    // ---- register-resident constants (no LDS dependency) ----
    float w1r[8];
#pragma unroll
    for (int k = 0; k < 8; k++) w1r[k] = ldv(mW1, k * 64 + lane, isbf);
    const float b1r = ldv(mB1, lane, isbf);
    float b3r[4];
#pragma unroll
    for (int r = 0; r < 4; r++) b3r[r] = ldv(isMean ? aB3 : vB3, r, isbf);

    const u16* wH1 = isMean ? lwH1m : lwH1v;
    const u16* wH2 = isMean ? lwH2m : lwH2v;
    const float* bAgg = biasL;
    const float* bH1  = isMean ? (biasL + 64)  : (biasL + 192);
    const float* bH2  = isMean ? (biasL + 128) : (biasL + 256);

    // W3^T A-fragments in registers (16x64 padded; rows>=4 zero)
    const void* W3src = isMean ? aW3 : vW3;
    short4v eA[4];
#pragma unroll
    for (int kb = 0; kb < 4; kb++) {
        union { short4v v; u16 s[4]; } pk;
#pragma unroll
        for (int j = 0; j < 4; j++) {
            int k = kb * 16 + quad * 4 + j;
            pk.s[j] = (ln15 < 4)
                ? (isbf ? ((const u16*)W3src)[k * 4 + ln15]
                        : f2bf_fast(((const float*)W3src)[k * 4 + ln15]))
                : (u16)0;
        }
        eA[kb] = pk.v;
    }

    __syncthreads();   // one-time staging visible

    const int myNode = nb * 16 + ln15;
    const float ngp = (myNode < NN) ? (float)__popc(gmaskS[myNode]) : 0.f;

    // transposed-chain layer: register B-frag in, register B-frag out
    auto runLayer = [&](const u16* wl, const float* bl, const short4v* Bin,
                        short4v* Bout, float bscale, bool doRelu) {
#pragma unroll
        for (int fb = 0; fb < 4; fb++) {
            f32x4 acc = {0.f, 0.f, 0.f, 0.f};
#pragma unroll
            for (int kb = 0; kb < 4; kb++) {
                short4v a = *(const short4v*)&wl[(fb * 16 + ln15) * WST + kb * 16 + quad * 4];
                acc = MFMA16(a, Bin[kb], acc);
            }
            float4 bv = *(const float4*)&bl[fb * 16 + quad * 4];
            union { short4v v; u16 s[4]; } pk;
#pragma unroll
            for (int r = 0; r < 4; r++) {
                float val = acc[r] + bscale * (&bv.x)[r];
                if (doRelu) val = fmaxf(val, 0.f);
                pk.s[r] = f2bf_fast(val);
            }
            Bout[fb] = pk.v;
        }
    };

    const half2v zero2 = {(_Float16)0.f, (_Float16)0.f};

    for (int step = 0; step < 2; step++) {
        // ================= merged EDGE phase: both channels =================
        {
            // pJ pairs for both channels in registers (per-wave redundant)
            half2v pJp0[15], pJp1[15];
#pragma unroll
            for (int m = 0; m < 15; m++) {
                float4 xa0 = *(const float4*)&xN[set][0][(2 * m) * 4];
                float4 xb0 = *(const float4*)&xN[set][0][(2 * m + 1) * 4];
                float4 xa1 = *(const float4*)&xN[set][1][(2 * m) * 4];
                float4 xb1 = *(const float4*)&xN[set][1][(2 * m + 1) * 4];
                half2v p0, p1;
                p0.x = (_Float16)(xa0.x * w1r[4] + xa0.y * w1r[5] + xa0.z * w1r[6] + xa0.w * w1r[7]);
                p0.y = (_Float16)(xb0.x * w1r[4] + xb0.y * w1r[5] + xb0.z * w1r[6] + xb0.w * w1r[7]);
                p1.x = (_Float16)(xa1.x * w1r[4] + xa1.y * w1r[5] + xa1.z * w1r[6] + xa1.w * w1r[7]);
                p1.y = (_Float16)(xb1.x * w1r[4] + xb1.y * w1r[5] + xb1.z * w1r[6] + xb1.w * w1r[7]);
                pJp0[m] = p0; pJp1[m] = p1;
            }

            // rows: two channels per iteration -> two independent dot2 chains,
            // shared mask SALU (both channels use the same bs graph)
            for (int i = swv; i < NN; i += 4) {
                float4 xv0 = *(const float4*)&xN[set][0][i * 4];
                float4 xv1 = *(const float4*)&xN[set][1][i * 4];
                float pI0 = b1r + xv0.x * w1r[0] + xv0.y * w1r[1] + xv0.z * w1r[2] + xv0.w * w1r[3];
                float pI1 = b1r + xv1.x * w1r[0] + xv1.y * w1r[1] + xv1.z * w1r[2] + xv1.w * w1r[3];
                _Float16 ph0 = (_Float16)pI0, ph1 = (_Float16)pI1;
                half2v pIp0 = {ph0, ph0}, pIp1 = {ph1, ph1};
                u32 gm = gmaskS[i];
                // remap edge-bit e -> node j (j = e + (e>=i)): bit i becomes 0
                u32 lowm = (1u << i) - 1u;
                u32 m2 = __builtin_amdgcn_readfirstlane((gm & lowm) | ((gm & ~lowm) << 1));
                float s00 = 0.f, s01 = 0.f, s10 = 0.f, s11 = 0.f;
#pragma unroll
                for (int m = 0; m < 15; m++) {
                    half2v t0 = pIp0 + pJp0[m];                    // v_pk_add_f16
                    half2v t1 = pIp1 + pJp1[m];
                    t0 = __builtin_elementwise_max(t0, zero2);     // v_pk_max_f16
                    t1 = __builtin_elementwise_max(t1, zero2);
#if __has_builtin(__builtin_amdgcn_fdot2)
                    u32 mm = ((m2 >> (2 * m)) & 1u) * 0x3C00u
                           + ((m2 >> (2 * m + 1)) & 1u) * 0x3C000000u;
                    half2v mv = __builtin_bit_cast(half2v, mm);
                    if (m & 1) { s01 = __builtin_amdgcn_fdot2(t0, mv, s01, false);
                                 s11 = __builtin_amdgcn_fdot2(t1, mv, s11, false); }
                    else       { s00 = __builtin_amdgcn_fdot2(t0, mv, s00, false);
                                 s10 = __builtin_amdgcn_fdot2(t1, mv, s10, false); }
#else
                    u32 mb = ((m2 >> (2 * m)) & 1u) * 0xFFFFu
                           + ((m2 >> (2 * m + 1)) & 1u) * 0xFFFF0000u;
                    u32 tb0 = __builtin_bit_cast(u32, t0) & mb;
                    u32 tb1 = __builtin_bit_cast(u32, t1) & mb;
                    half2v tv0 = __builtin_bit_cast(half2v, tb0);
                    half2v tv1 = __builtin_bit_cast(half2v, tb1);
                    s00 += (float)tv0.x; s01 += (float)tv0.y;
                    s10 += (float)tv1.x; s11 += (float)tv1.y;
#endif
                }
                S[set * NCPB + 0][i * AST + lane] = f2bf_fast(s00 + s01);
                S[set * NCPB + 1][i * AST + lane] = f2bf_fast(s10 + s11);
            }
        }
        __syncthreads();

        // ================= merged MLP phase: both channels =================
#pragma unroll
        for (int ci = 0; ci < NCPB; ci++) {
            const u16* Sb = S[set * NCPB + ci];
            short4v Bs[4], Ba[4], Bb[4];
#pragma unroll
            for (int kb = 0; kb < 4; kb++)
                Bs[kb] = *(const short4v*)&Sb[(nb * 16 + ln15) * AST + kb * 16 + quad * 4];

            runLayer(lwM2, bAgg, Bs, Ba, ngp, false);   // agg = S@W2 + ng*b2
            runLayer(wH1,  bH1,  Ba, Bb, 1.f, true);    // h1 = relu(agg@W1+b1)
            runLayer(wH2,  bH2,  Bb, Ba, 1.f, true);    // h2 = relu(h1@W2+b2)

            // out layer: D = W3T(reg) @ h2^T
            f32x4 acc = {0.f, 0.f, 0.f, 0.f};
#pragma unroll
            for (int kb = 0; kb < 4; kb++) acc = MFMA16(eA[kb], Ba[kb], acc);
            const int n = nb * 16 + ln15;
            const int c = cg * NCPB + ci;
            const int t = 2 * c + step;
            if (quad == 0 && n < NN) {
                float v[4];
#pragma unroll
                for (int r = 0; r < 4; r++) v[r] = acc[r] + b3r[r];
                if (!isMean) {
#pragma unroll
                    for (int r = 0; r < 4; r++) v[r] = softplus_clip(v[r]);
                }
                if (t < 127) {
                    size_t o = (size_t)bs * TSTRIDE + (size_t)t * NF + n * 4
                             + (isMean ? 0 : OUTHALF);
                    if (isbf) {
                        u16* op = (u16*)out;
                        u32 lo = (u32)f2bf_fast(v[0]) | ((u32)f2bf_fast(v[1]) << 16);
                        u32 hi = (u32)f2bf_fast(v[2]) | ((u32)f2bf_fast(v[3]) << 16);
                        *(u32*)&op[o] = lo;
                        *(u32*)&op[o + 2] = hi;
                    } else {
                        float* op = (float*)out;
                        op[o] = v[0]; op[o+1] = v[1]; op[o+2] = v[2]; op[o+3] = v[3];
                    }
                }
                if (isMean && step == 0) {
                    xN[set][ci][n*4]   = v[0]; xN[set][ci][n*4+1] = v[1];
                    xN[set][ci][n*4+2] = v[2]; xN[set][ci][n*4+3] = v[3];
                }
            }
        }
        __syncthreads();   // xN/S step boundary
    }
}

extern "C" void kernel_launch(void* const* d_in, const int* in_sizes, int n_in,
                              void* d_out, int out_size, void* d_ws, size_t ws_size,
                              hipStream_t stream) {
    (void)in_sizes; (void)n_in; (void)out_size; (void)d_ws; (void)ws_size;

    const void* data  = d_in[0];
    const void* graph = d_in[1];
    const void* mW1 = d_in[2];  const void* mB1 = d_in[3];
    const void* mW2 = d_in[4];  const void* mB2 = d_in[5];
    const void* aW1 = d_in[6];  const void* aB1 = d_in[7];
    const void* aW2 = d_in[8];  const void* aB2 = d_in[9];
    const void* aW3 = d_in[10]; const void* aB3 = d_in[11];
    const void* vW1 = d_in[12]; const void* vB1 = d_in[13];
    const void* vW2 = d_in[14]; const void* vB2 = d_in[15];
    const void* vW3 = d_in[16]; const void* vB3 = d_in[17];

    sim_fused<<<BSZ * BPB, 1024, 0, stream>>>(data, graph,
        mW1, mB1, mW2, mB2,
        aW1, aB1, aW2, aB2, aW3, aB3,
        vW1, vB1, vW2, vB2, vW3, vB3,
        d_out);
}